// Round 1
// baseline (7451.668 us; speedup 1.0000x reference)
//
#include <hip/hip_runtime.h>
#include <math.h>

#define NN 20000
#define EE 320000
#define LDIM 128
#define MM 16
#define HDD 16
#define NII 64
#define EPSN 1e-5f
#define INV_SQRT3 0.5773502691896258f
#define INV_SQRT2 0.7071067811865476f

__device__ __forceinline__ float wsum64(float v) {
#pragma unroll
  for (int o = 1; o < 64; o <<= 1) v += __shfl_xor(v, o, 64);
  return v;
}
// monotonic float<->uint encoding for atomicMax on floats (incl. negatives)
__device__ __forceinline__ unsigned fenc(float f) {
  unsigned u = __float_as_uint(f);
  return (u & 0x80000000u) ? ~u : (u | 0x80000000u);
}
__device__ __forceinline__ float fdec(unsigned k) {
  unsigned u = (k & 0x80000000u) ? (k & 0x7FFFFFFFu) : ~k;
  return __uint_as_float(u);
}
__device__ __forceinline__ float silu(float x) { return x / (1.0f + expf(-x)); }

// ---------------- init node buffers (ws is poisoned each run) ----------------
__global__ void k_init(unsigned* __restrict__ nmax, float* __restrict__ nsum,
                       float* __restrict__ nds, float* __restrict__ ndv) {
  int i = blockIdx.x * 256 + threadIdx.x;
  if (i < NN * 16) {
    nmax[i] = 0x007FFFFFu;  // fenc(-inf)
    nsum[i] = 0.0f;
    nds[i] = 0.0f;
  }
  if (i < NN * 48) ndv[i] = 0.0f;
}

// ---------------- front half: env MLP + q/k + logits, per-edge wave ----------
__global__ __launch_bounds__(256) void k_edge_front(
    const float* __restrict__ scal, const float* __restrict__ ninv,
    const int* __restrict__ ecent,
    const float* __restrict__ w1, const float* __restrict__ b1,
    const float* __restrict__ w2, const float* __restrict__ b2,
    const float* __restrict__ w3, const float* __restrict__ b3,
    const float* __restrict__ wq, const float* __restrict__ wk,
    float* __restrict__ gates, float* __restrict__ logits,
    unsigned* __restrict__ nmax) {
  const int wid = threadIdx.x >> 6, lane = threadIdx.x & 63;
  const int e = blockIdx.x * 4 + wid;  // EE % 4 == 0, no tail
  __shared__ float XS[4][LDIM], H1S[4][LDIM], H2S[4][LDIM], NIS[4][NII],
      QS[4][256], KS[4][256];
  float* X = XS[wid];
  float* h1 = H1S[wid];
  float* h2 = H2S[wid];
  float* ni = NIS[wid];
  float* Q = QS[wid];
  float* K = KS[wid];
  const int c = ecent[e];
  {
    float2 xv = ((const float2*)scal)[(size_t)e * 64 + lane];
    X[2 * lane] = xv.x;
    X[2 * lane + 1] = xv.y;
    ni[lane] = ninv[c * NII + lane];
  }
  __syncthreads();
  // K projection: 4 outputs/lane from X (128 -> 256)
  {
    float k0 = 0, k1 = 0, k2 = 0, k3 = 0;
#pragma unroll 4
    for (int i = 0; i < LDIM; i++) {
      float xv = X[i];
      float4 w = ((const float4*)wk)[i * 64 + lane];
      k0 += xv * w.x; k1 += xv * w.y; k2 += xv * w.z; k3 += xv * w.w;
    }
    K[4 * lane] = k0; K[4 * lane + 1] = k1; K[4 * lane + 2] = k2; K[4 * lane + 3] = k3;
  }
  // Q projection: 4 outputs/lane from ni (64 -> 256)
  {
    float q0 = 0, q1 = 0, q2 = 0, q3 = 0;
#pragma unroll 4
    for (int i = 0; i < NII; i++) {
      float nv = ni[i];
      float4 w = ((const float4*)wq)[i * 64 + lane];
      q0 += nv * w.x; q1 += nv * w.y; q2 += nv * w.z; q3 += nv * w.w;
    }
    Q[4 * lane] = q0; Q[4 * lane + 1] = q1; Q[4 * lane + 2] = q2; Q[4 * lane + 3] = q3;
  }
  // env layer 1 (128 -> 128), 2 outputs/lane
  {
    float2 b = ((const float2*)b1)[lane];
    float a0 = b.x, a1 = b.y;
#pragma unroll 4
    for (int i = 0; i < LDIM; i++) {
      float xv = X[i];
      float2 w = ((const float2*)w1)[i * 64 + lane];
      a0 += xv * w.x; a1 += xv * w.y;
    }
    h1[2 * lane] = silu(a0);
    h1[2 * lane + 1] = silu(a1);
  }
  __syncthreads();
  // env layer 2 (128 -> 128)
  {
    float2 b = ((const float2*)b2)[lane];
    float a0 = b.x, a1 = b.y;
#pragma unroll 4
    for (int i = 0; i < LDIM; i++) {
      float xv = h1[i];
      float2 w = ((const float2*)w2)[i * 64 + lane];
      a0 += xv * w.x; a1 += xv * w.y;
    }
    h2[2 * lane] = silu(a0);
    h2[2 * lane + 1] = silu(a1);
  }
  __syncthreads();
  // gates (128 -> 32): split the i-range over lane halves, combine via shuffle
  {
    const int j = lane & 31, half = lane >> 5;
    float g = 0;
#pragma unroll 4
    for (int i = half * 64; i < half * 64 + 64; i++) g += h2[i] * w3[i * 32 + j];
    g += __shfl_xor(g, 32, 64);
    if (lane < 32) gates[(size_t)e * 32 + lane] = g + b3[lane];
  }
  // logits[m] = 4 * dot(q[m,:], k[m,:])   (isqrt(16) == 4, and it MULTIPLIES)
  if (lane < MM) {
    float l = 0;
#pragma unroll
    for (int d = 0; d < HDD; d++) l += Q[lane * 16 + d] * K[lane * 16 + d];
    l *= 4.0f;
    logits[(size_t)e * 16 + lane] = l;
    atomicMax(&nmax[c * 16 + lane], fenc(l));
  }
}

// ---------------- softmax denominator ----------------------------------------
__global__ void k_softmax_sum(const int* __restrict__ ecent,
                              const float* __restrict__ logits,
                              const unsigned* __restrict__ nmax,
                              float* __restrict__ nsum) {
  int t = blockIdx.x * 256 + threadIdx.x;  // t < EE*16
  int e = t >> 4, m = t & 15;
  int c = ecent[e];
  float ew = expf(logits[t] - fdec(nmax[c * 16 + m]));
  atomicAdd(&nsum[c * 16 + m], ew);
}

// ---------------- attn-weighted scatter into node_s / node_v -----------------
__global__ void k_scatter(const int* __restrict__ ecent,
                          const float* __restrict__ logits,
                          const unsigned* __restrict__ nmax,
                          const float* __restrict__ nsum,
                          const float* __restrict__ gates,
                          const float* __restrict__ equiv,
                          float* __restrict__ nds, float* __restrict__ ndv) {
  int t = blockIdx.x * 256 + threadIdx.x;  // t < EE*16
  int e = t >> 4, m = t & 15;
  int c = ecent[e];
  float ew = expf(logits[t] - fdec(nmax[c * 16 + m]));
  float attn = ew / (nsum[c * 16 + m] + 1e-12f);
  float g0 = gates[(size_t)e * 32 + 2 * m];
  float g1 = gates[(size_t)e * 32 + 2 * m + 1];
  float4 q = ((const float4*)equiv)[t];  // equiv[e, m, 0:4]
  atomicAdd(&nds[c * 16 + m], g0 * q.x * attn);
  atomicAdd(&ndv[c * 48 + 3 * m + 0], g1 * q.y * attn);
  atomicAdd(&ndv[c * 48 + 3 * m + 1], g1 * q.z * attn);
  atomicAdd(&ndv[c * 48 + 3 * m + 2], g1 * q.w * attn);
}

// ---------------- per-node irrep norm ----------------------------------------
__global__ __launch_bounds__(256) void k_nodenorm(float* __restrict__ nds,
                                                  float* __restrict__ ndv) {
  const int wid = threadIdx.x >> 6, lane = threadIdx.x & 63;
  const int n = blockIdx.x * 4 + wid;  // NN % 4 == 0
  float sv = (lane < 16) ? nds[n * 16 + lane] : 0.0f;
  float ss = wsum64(sv * sv);
  float vv = (lane < 48) ? ndv[n * 48 + lane] : 0.0f;
  float vs = wsum64(vv * vv);
  if (lane < 16) nds[n * 16 + lane] = sv * rsqrtf(ss * (1.0f / 16) + EPSN);
  if (lane < 48) ndv[n * 48 + lane] = vv * rsqrtf(vs * (1.0f / 48) + EPSN);
}

// ---------------- back half: tensor products + sc MLP + outputs --------------
__global__ __launch_bounds__(256) void k_edge_back(
    const float* __restrict__ scal, const float* __restrict__ equiv,
    const int* __restrict__ ecent, const int* __restrict__ act,
    const float* __restrict__ ucoef, const float* __restrict__ nds,
    const float* __restrict__ ndv,
    const float* __restrict__ scw1, const float* __restrict__ scb1,
    const float* __restrict__ scw2, const float* __restrict__ scb2,
    const float* __restrict__ scw3, const float* __restrict__ scb3,
    const float* __restrict__ lng, const float* __restrict__ lnb,
    const float* __restrict__ weqs, const float* __restrict__ weqv,
    float* __restrict__ outs, float* __restrict__ oute) {
  const int wid = threadIdx.x >> 6, lane = threadIdx.x & 63;
  const int e = blockIdx.x * 4 + wid;
  __shared__ float ASs[4][16], AVs[4][48], BSs[4][16], BVs[4][48], V1s[4][48],
      V2s[4][48], V3s[4][48], S1s[4][16], S2s[4][16], SCIs[4][32],
      H1s[4][128], H2s[4][128];
  float* as_ = ASs[wid]; float* av_ = AVs[wid];
  float* bs_ = BSs[wid]; float* bv_ = BVs[wid];
  float* v1_ = V1s[wid]; float* v2_ = V2s[wid]; float* v3_ = V3s[wid];
  float* s1_ = S1s[wid]; float* s2_ = S2s[wid];
  float* sci_ = SCIs[wid]; float* h1_ = H1s[wid]; float* h2_ = H2s[wid];
  const int c = ecent[e];
  {
    float ev = equiv[(size_t)e * 64 + lane];
    int m = lane >> 2, cc = lane & 3;
    if (cc == 0) as_[m] = ev; else av_[m * 3 + cc - 1] = ev;
    if (lane < 16) bs_[lane] = nds[c * 16 + lane];
    if (lane < 48) bv_[lane] = ndv[c * 48 + lane];
  }
  __syncthreads();
  {
    int role = lane >> 4, m = lane & 15;
    if (role == 0) {
      s1_[m] = as_[m] * bs_[m];
      s2_[m] = (av_[3 * m] * bv_[3 * m] + av_[3 * m + 1] * bv_[3 * m + 1] +
                av_[3 * m + 2] * bv_[3 * m + 2]) * INV_SQRT3;
    } else if (role == 1) {
      v1_[3 * m] = as_[m] * bv_[3 * m];
      v1_[3 * m + 1] = as_[m] * bv_[3 * m + 1];
      v1_[3 * m + 2] = as_[m] * bv_[3 * m + 2];
    } else if (role == 2) {
      v2_[3 * m] = av_[3 * m] * bs_[m];
      v2_[3 * m + 1] = av_[3 * m + 1] * bs_[m];
      v2_[3 * m + 2] = av_[3 * m + 2] * bs_[m];
    } else {
      float ax = av_[3 * m], ay = av_[3 * m + 1], az = av_[3 * m + 2];
      float bx = bv_[3 * m], by = bv_[3 * m + 1], bz = bv_[3 * m + 2];
      v3_[3 * m] = (ay * bz - az * by) * INV_SQRT2;
      v3_[3 * m + 1] = (az * bx - ax * bz) * INV_SQRT2;
      v3_[3 * m + 2] = (ax * by - ay * bx) * INV_SQRT2;
    }
  }
  __syncthreads();
  float p;
  p = (lane < 16) ? s1_[lane] * s1_[lane] : 0.0f; float s1s = wsum64(p);
  p = (lane < 16) ? s2_[lane] * s2_[lane] : 0.0f; float s2s = wsum64(p);
  p = (lane < 48) ? v1_[lane] * v1_[lane] : 0.0f; float v1s = wsum64(p);
  p = (lane < 48) ? v2_[lane] * v2_[lane] : 0.0f; float v2s = wsum64(p);
  p = (lane < 48) ? v3_[lane] * v3_[lane] : 0.0f; float v3s = wsum64(p);
  float r1 = rsqrtf(s1s * (1.0f / 16) + EPSN), r2 = rsqrtf(s2s * (1.0f / 16) + EPSN);
  float rv1 = rsqrtf(v1s * (1.0f / 48) + EPSN), rv2 = rsqrtf(v2s * (1.0f / 48) + EPSN),
        rv3 = rsqrtf(v3s * (1.0f / 48) + EPSN);
  if (lane < 16) {
    float a = s1_[lane] * r1, b = s2_[lane] * r2;
    s1_[lane] = a; s2_[lane] = b;
    sci_[2 * lane] = a; sci_[2 * lane + 1] = b;  // stacked-interleaved scalars
  } else {
    int i = lane - 16;  // exactly 48 lanes
    v1_[i] *= rv1; v2_[i] *= rv2; v3_[i] *= rv3;
  }
  __syncthreads();
  // sc layer 1 (32 -> 128)
  float o0, o1;
  {
    float2 b = ((const float2*)scb1)[lane];
    float a0 = b.x, a1 = b.y;
#pragma unroll
    for (int i = 0; i < 32; i++) {
      float xv = sci_[i];
      float2 w = ((const float2*)scw1)[i * 64 + lane];
      a0 += xv * w.x; a1 += xv * w.y;
    }
    h1_[2 * lane] = silu(a0); h1_[2 * lane + 1] = silu(a1);
  }
  __syncthreads();
  // sc layer 2 (128 -> 128)
  {
    float2 b = ((const float2*)scb2)[lane];
    float a0 = b.x, a1 = b.y;
#pragma unroll 4
    for (int i = 0; i < LDIM; i++) {
      float xv = h1_[i];
      float2 w = ((const float2*)scw2)[i * 64 + lane];
      a0 += xv * w.x; a1 += xv * w.y;
    }
    h2_[2 * lane] = silu(a0); h2_[2 * lane + 1] = silu(a1);
  }
  __syncthreads();
  // sc layer 3 (128 -> 128), no activation
  {
    float2 b = ((const float2*)scb3)[lane];
    o0 = b.x; o1 = b.y;
#pragma unroll 4
    for (int i = 0; i < LDIM; i++) {
      float xv = h2_[i];
      float2 w = ((const float2*)scw3)[i * 64 + lane];
      o0 += xv * w.x; o1 += xv * w.y;
    }
  }
  // LayerNorm over 128
  float sm = wsum64(o0 + o1);
  float sq = wsum64(o0 * o0 + o1 * o1);
  float mu = sm * (1.0f / 128);
  float var = sq * (1.0f / 128) - mu * mu;
  float rs = rsqrtf(var + EPSN);
  float2 g2 = ((const float2*)lng)[lane], bb2 = ((const float2*)lnb)[lane];
  float n0 = (o0 - mu) * rs * g2.x + bb2.x;
  float n1 = (o1 - mu) * rs * g2.y + bb2.y;
  float ucv = ucoef[0];
  float co = rsqrtf(ucv * ucv + 1.0f), cn = ucv * co;
  int ae = act[e];
  {
    float2 xv = ((const float2*)scal)[(size_t)ae * 64 + lane];
    float2 ov;
    ov.x = co * xv.x + cn * n0;
    ov.y = co * xv.y + cn * n1;
    ((float2*)outs)[(size_t)ae * 64 + lane] = ov;
  }
  // eq_s: CONCATENATED [s1, s2] @ weq_s  -> equiv_out[..., 0]
  if (lane < 16) {
    float acc = 0;
#pragma unroll
    for (int i = 0; i < 16; i++) acc += s1_[i] * weqs[i * 16 + lane];
#pragma unroll
    for (int i = 0; i < 16; i++) acc += s2_[i] * weqs[(16 + i) * 16 + lane];
    oute[(size_t)e * 64 + lane * 4] = acc;
  }
  // eq_v: concat(v1,v2,v3) (48,3) einsum weq_v (48,16) -> equiv_out[..., 1:4]
  if (lane < 48) {
    int m2 = lane / 3, c2 = lane - 3 * m2;
    float acc = 0;
#pragma unroll
    for (int i = 0; i < 16; i++) acc += v1_[3 * i + c2] * weqv[i * 16 + m2];
#pragma unroll
    for (int i = 0; i < 16; i++) acc += v2_[3 * i + c2] * weqv[(16 + i) * 16 + m2];
#pragma unroll
    for (int i = 0; i < 16; i++) acc += v3_[3 * i + c2] * weqv[(32 + i) * 16 + m2];
    oute[(size_t)e * 64 + m2 * 4 + 1 + c2] = acc;
  }
}

extern "C" void kernel_launch(void* const* d_in, const int* in_sizes, int n_in,
                              void* d_out, int out_size, void* d_ws,
                              size_t ws_size, hipStream_t stream) {
  const float* ninv = (const float*)d_in[0];
  const float* scal = (const float*)d_in[1];
  const float* equiv = (const float*)d_in[2];
  const int* eidx = (const int*)d_in[3];
  const int* act = (const int*)d_in[4];
  const float* uc = (const float*)d_in[5];
  const float* ew1 = (const float*)d_in[6];
  const float* eb1 = (const float*)d_in[7];
  const float* ew2 = (const float*)d_in[8];
  const float* eb2 = (const float*)d_in[9];
  const float* ew3 = (const float*)d_in[10];
  const float* eb3 = (const float*)d_in[11];
  const float* wq = (const float*)d_in[12];
  const float* wk = (const float*)d_in[13];
  const float* sw1 = (const float*)d_in[14];
  const float* sb1 = (const float*)d_in[15];
  const float* sw2 = (const float*)d_in[16];
  const float* sb2 = (const float*)d_in[17];
  const float* sw3 = (const float*)d_in[18];
  const float* sb3 = (const float*)d_in[19];
  const float* lng = (const float*)d_in[20];
  const float* lnb = (const float*)d_in[21];
  const float* weqs = (const float*)d_in[22];
  const float* weqv = (const float*)d_in[23];

  float* outs = (float*)d_out;
  float* oute = outs + (size_t)EE * 128;

  float* ws = (float*)d_ws;
  float* gates = ws;                                    // E*32
  float* logits = ws + (size_t)EE * 32;                 // E*16
  unsigned* nmax = (unsigned*)(ws + (size_t)EE * 48);   // N*16
  float* nsum = ws + (size_t)EE * 48 + NN * 16;         // N*16
  float* nds = ws + (size_t)EE * 48 + NN * 32;          // N*16
  float* ndv = ws + (size_t)EE * 48 + NN * 48;          // N*48

  const int* ecent = eidx;  // edge_index[0] = first E ints of (2,E)

  hipLaunchKernelGGL(k_init, dim3((NN * 48 + 255) / 256), dim3(256), 0, stream,
                     nmax, nsum, nds, ndv);
  hipLaunchKernelGGL(k_edge_front, dim3(EE / 4), dim3(256), 0, stream, scal,
                     ninv, ecent, ew1, eb1, ew2, eb2, ew3, eb3, wq, wk, gates,
                     logits, nmax);
  hipLaunchKernelGGL(k_softmax_sum, dim3(EE * 16 / 256), dim3(256), 0, stream,
                     ecent, logits, nmax, nsum);
  hipLaunchKernelGGL(k_scatter, dim3(EE * 16 / 256), dim3(256), 0, stream,
                     ecent, logits, nmax, nsum, gates, equiv, nds, ndv);
  hipLaunchKernelGGL(k_nodenorm, dim3(NN / 4), dim3(256), 0, stream, nds, ndv);
  hipLaunchKernelGGL(k_edge_back, dim3(EE / 4), dim3(256), 0, stream, scal,
                     equiv, ecent, act, uc, nds, ndv, sw1, sb1, sw2, sb2, sw3,
                     sb3, lng, lnb, weqs, weqv, outs, oute);
}

// Round 3
// 2247.411 us; speedup vs baseline: 3.3157x; 3.3157x over previous
//
#include <hip/hip_runtime.h>
#include <math.h>

#define NN 20000
#define EE 320000
#define EPSN 1e-5f
#define INV_SQRT3 0.5773502691896258f
#define INV_SQRT2 0.7071067811865476f

__device__ __forceinline__ float wsum64(float v) {
#pragma unroll
  for (int o = 1; o < 64; o <<= 1) v += __shfl_xor(v, o, 64);
  return v;
}
__device__ __forceinline__ unsigned fenc(float f) {
  unsigned u = __float_as_uint(f);
  return (u & 0x80000000u) ? ~u : (u | 0x80000000u);
}
__device__ __forceinline__ float fdec(unsigned k) {
  unsigned u = (k & 0x80000000u) ? (k & 0x7FFFFFFFu) : ~k;
  return __uint_as_float(u);
}
__device__ __forceinline__ float silu(float x) { return x / (1.0f + expf(-x)); }

// ---------------- init node buffers ------------------------------------------
__global__ void k_init(unsigned* __restrict__ nmax, float* __restrict__ nsum,
                       float* __restrict__ nds, float* __restrict__ ndv) {
  int i = blockIdx.x * 256 + threadIdx.x;
  if (i < NN * 16) {
    nmax[i] = 0x007FFFFFu;  // fenc(-inf)
    nsum[i] = 0.0f;
    nds[i] = 0.0f;
  }
  if (i < NN * 48) ndv[i] = 0.0f;
}

// ---------------- front half: 8 edges per wave, weights amortized ------------
__global__ __launch_bounds__(256) void k_edge_front(
    const float* __restrict__ scal, const float* __restrict__ ninv,
    const int* __restrict__ ecent,
    const float* __restrict__ w1, const float* __restrict__ b1,
    const float* __restrict__ w2, const float* __restrict__ b2,
    const float* __restrict__ w3, const float* __restrict__ b3,
    const float* __restrict__ wq, const float* __restrict__ wk,
    float* __restrict__ gates, float* __restrict__ logits,
    unsigned* __restrict__ nmax) {
  const int wid = threadIdx.x >> 6, lane = threadIdx.x & 63;
  const int e0 = (blockIdx.x * 4 + wid) * 8;
  __shared__ float XS[4][8][128];   // X, later reused as h2
  __shared__ float NIS[4][8][64];
  __shared__ float H1S[4][8][128];
  float* X = &XS[wid][0][0];
  float* NI = &NIS[wid][0][0];
  float* H1 = &H1S[wid][0][0];

  int cidx[8];
#pragma unroll
  for (int j = 0; j < 8; j++) {
    cidx[j] = ecent[e0 + j];
    ((float2*)X)[j * 64 + lane] = ((const float2*)scal)[(size_t)(e0 + j) * 64 + lane];
    NI[j * 64 + lane] = ninv[(size_t)cidx[j] * 64 + lane];
  }

  // ---- K projection (128 -> 256), lane owns cols 4l..4l+3 ----
  float kk[8][4];
#pragma unroll
  for (int j = 0; j < 8; j++) { kk[j][0] = kk[j][1] = kk[j][2] = kk[j][3] = 0.f; }
  for (int i = 0; i < 128; i += 2) {
    float4 wa = ((const float4*)wk)[(size_t)i * 64 + lane];
    float4 wb = ((const float4*)wk)[(size_t)(i + 1) * 64 + lane];
#pragma unroll
    for (int j = 0; j < 8; j++) {
      float2 xv = *(const float2*)(X + j * 128 + i);
      kk[j][0] += xv.x * wa.x + xv.y * wb.x;
      kk[j][1] += xv.x * wa.y + xv.y * wb.y;
      kk[j][2] += xv.x * wa.z + xv.y * wb.z;
      kk[j][3] += xv.x * wa.w + xv.y * wb.w;
    }
  }

  // ---- env layer 1 (128 -> 128), lane owns cols 2l,2l+1 ----
  {
    float2 bb = ((const float2*)b1)[lane];
    float aa[8][2];
#pragma unroll
    for (int j = 0; j < 8; j++) { aa[j][0] = bb.x; aa[j][1] = bb.y; }
    for (int i = 0; i < 128; i += 2) {
      float2 wc0 = ((const float2*)w1)[(size_t)i * 64 + lane];
      float2 wc1 = ((const float2*)w1)[(size_t)(i + 1) * 64 + lane];
#pragma unroll
      for (int j = 0; j < 8; j++) {
        float2 xv = *(const float2*)(X + j * 128 + i);
        aa[j][0] += xv.x * wc0.x + xv.y * wc1.x;
        aa[j][1] += xv.x * wc0.y + xv.y * wc1.y;
      }
    }
#pragma unroll
    for (int j = 0; j < 8; j++)
      ((float2*)H1)[j * 64 + lane] = make_float2(silu(aa[j][0]), silu(aa[j][1]));
  }

  // ---- Q projection (64 -> 256) ----
  float qq[8][4];
#pragma unroll
  for (int j = 0; j < 8; j++) { qq[j][0] = qq[j][1] = qq[j][2] = qq[j][3] = 0.f; }
  for (int i = 0; i < 64; i += 2) {
    float4 wa = ((const float4*)wq)[(size_t)i * 64 + lane];
    float4 wb = ((const float4*)wq)[(size_t)(i + 1) * 64 + lane];
#pragma unroll
    for (int j = 0; j < 8; j++) {
      float2 nv = *(const float2*)(NI + j * 64 + i);
      qq[j][0] += nv.x * wa.x + nv.y * wb.x;
      qq[j][1] += nv.x * wa.y + nv.y * wb.y;
      qq[j][2] += nv.x * wa.z + nv.y * wb.z;
      qq[j][3] += nv.x * wa.w + nv.y * wb.w;
    }
  }

  // ---- logits[m] = 4 * dot(q[m,:], k[m,:]); reduce over 4-lane groups ----
#pragma unroll
  for (int j = 0; j < 8; j++) {
    float p = qq[j][0] * kk[j][0] + qq[j][1] * kk[j][1] +
              qq[j][2] * kk[j][2] + qq[j][3] * kk[j][3];
    p += __shfl_xor(p, 1);
    p += __shfl_xor(p, 2);
    if ((lane & 3) == 0) {
      float lg = 4.0f * p;
      logits[(size_t)(e0 + j) * 16 + (lane >> 2)] = lg;
      atomicMax(&nmax[cidx[j] * 16 + (lane >> 2)], fenc(lg));
    }
  }

  // ---- env layer 2 (128 -> 128), h2 overwrites X ----
  {
    float2 bb = ((const float2*)b2)[lane];
    float aa[8][2];
#pragma unroll
    for (int j = 0; j < 8; j++) { aa[j][0] = bb.x; aa[j][1] = bb.y; }
    for (int i = 0; i < 128; i += 2) {
      float2 wc0 = ((const float2*)w2)[(size_t)i * 64 + lane];
      float2 wc1 = ((const float2*)w2)[(size_t)(i + 1) * 64 + lane];
#pragma unroll
      for (int j = 0; j < 8; j++) {
        float2 xv = *(const float2*)(H1 + j * 128 + i);
        aa[j][0] += xv.x * wc0.x + xv.y * wc1.x;
        aa[j][1] += xv.x * wc0.y + xv.y * wc1.y;
      }
    }
#pragma unroll
    for (int j = 0; j < 8; j++)
      ((float2*)X)[j * 64 + lane] = make_float2(silu(aa[j][0]), silu(aa[j][1]));
  }

  // ---- gates (128 -> 32): halves of i-range over lane halves ----
  {
    const int col = lane & 31, half = lane >> 5;
    float g[8];
#pragma unroll
    for (int j = 0; j < 8; j++) g[j] = 0.f;
    for (int i = half * 64; i < half * 64 + 64; i += 2) {
      float wg0 = w3[i * 32 + col];
      float wg1 = w3[(i + 1) * 32 + col];
#pragma unroll
      for (int j = 0; j < 8; j++) {
        float2 hv = *(const float2*)(X + j * 128 + i);
        g[j] += hv.x * wg0 + hv.y * wg1;
      }
    }
#pragma unroll
    for (int j = 0; j < 8; j++) {
      g[j] += __shfl_xor(g[j], 32);
      if (lane < 32) gates[(size_t)(e0 + j) * 32 + lane] = g[j] + b3[lane];
    }
  }
}

// ---------------- fused exp + scatter (normalization deferred to nodenorm) ---
__global__ void k_scatter(const int* __restrict__ ecent,
                          const float* __restrict__ logits,
                          const unsigned* __restrict__ nmax,
                          const float* __restrict__ gates,
                          const float* __restrict__ equiv,
                          float* __restrict__ nsum,
                          float* __restrict__ nds, float* __restrict__ ndv) {
  int t = blockIdx.x * 256 + threadIdx.x;  // t < EE*16
  int e = t >> 4, m = t & 15;
  int c = ecent[e];
  float ew = expf(logits[t] - fdec(nmax[c * 16 + m]));
  atomicAdd(&nsum[c * 16 + m], ew);
  float2 gg = ((const float2*)gates)[(size_t)e * 16 + m];
  float4 q = ((const float4*)equiv)[t];
  atomicAdd(&nds[c * 16 + m], gg.x * q.x * ew);
  atomicAdd(&ndv[c * 48 + 3 * m + 0], gg.y * q.y * ew);
  atomicAdd(&ndv[c * 48 + 3 * m + 1], gg.y * q.z * ew);
  atomicAdd(&ndv[c * 48 + 3 * m + 2], gg.y * q.w * ew);
}

// ---------------- per-node: softmax-normalize + irrep norm + pack ------------
__global__ __launch_bounds__(256) void k_nodenorm(const float* __restrict__ nds,
                                                  const float* __restrict__ ndv,
                                                  const float* __restrict__ nsum,
                                                  float* __restrict__ ndb) {
  const int wid = threadIdx.x >> 6, lane = threadIdx.x & 63;
  const int n = blockIdx.x * 4 + wid;
  float sv = 0.f, vv = 0.f;
  int mv = lane / 3, cv = lane - 3 * mv;
  if (lane < 16) sv = nds[n * 16 + lane] / (nsum[n * 16 + lane] + 1e-12f);
  if (lane < 48) vv = ndv[n * 48 + lane] / (nsum[n * 16 + mv] + 1e-12f);
  float ss = wsum64((lane < 16) ? sv * sv : 0.f);
  float vs = wsum64((lane < 48) ? vv * vv : 0.f);
  float rs = rsqrtf(ss * (1.0f / 16) + EPSN);
  float rv = rsqrtf(vs * (1.0f / 48) + EPSN);
  if (lane < 16) ndb[(size_t)n * 64 + lane * 4] = sv * rs;
  if (lane < 48) ndb[(size_t)n * 64 + mv * 4 + 1 + cv] = vv * rv;
}

// ---------------- back half: 8 edges/wave; products lane-local ---------------
__global__ __launch_bounds__(256) void k_edge_back(
    const float* __restrict__ scal, const float* __restrict__ equiv,
    const int* __restrict__ ecent, const int* __restrict__ act,
    const float* __restrict__ ucoef, const float* __restrict__ ndb,
    const float* __restrict__ scw1, const float* __restrict__ scb1,
    const float* __restrict__ scw2, const float* __restrict__ scb2,
    const float* __restrict__ scw3, const float* __restrict__ scb3,
    const float* __restrict__ lng, const float* __restrict__ lnb,
    const float* __restrict__ weqs, const float* __restrict__ weqv,
    float* __restrict__ outs, float* __restrict__ oute) {
  const int wid = threadIdx.x >> 6, lane = threadIdx.x & 63;
  const int e0 = (blockIdx.x * 4 + wid) * 8;
  const int g = lane >> 3, r = lane & 7;
  const int e = e0 + g;
  __shared__ float SCIS[4][8][36];
  __shared__ float UNS[4][8][256];
  float* SCI = &SCIS[wid][0][0];
  float* UN = &UNS[wid][0][0];

  // load a (equiv) and b (packed node buffer); m = 2r (a4=qa) and 2r+1 (qb)
  const int c = ecent[e];
  float4 qa = ((const float4*)equiv)[(size_t)e * 16 + r * 2];
  float4 qb = ((const float4*)equiv)[(size_t)e * 16 + r * 2 + 1];
  float4 ba = ((const float4*)ndb)[(size_t)c * 16 + r * 2];
  float4 bb = ((const float4*)ndb)[(size_t)c * 16 + r * 2 + 1];

  float s1a = qa.x * ba.x, s1b = qb.x * bb.x;
  float s2a = (qa.y * ba.y + qa.z * ba.z + qa.w * ba.w) * INV_SQRT3;
  float s2b = (qb.y * bb.y + qb.z * bb.z + qb.w * bb.w) * INV_SQRT3;
  float v1a0 = qa.x * ba.y, v1a1 = qa.x * ba.z, v1a2 = qa.x * ba.w;
  float v1b0 = qb.x * bb.y, v1b1 = qb.x * bb.z, v1b2 = qb.x * bb.w;
  float v2a0 = qa.y * ba.x, v2a1 = qa.z * ba.x, v2a2 = qa.w * ba.x;
  float v2b0 = qb.y * bb.x, v2b1 = qb.z * bb.x, v2b2 = qb.w * bb.x;
  float v3a0 = (qa.z * ba.w - qa.w * ba.z) * INV_SQRT2;
  float v3a1 = (qa.w * ba.y - qa.y * ba.w) * INV_SQRT2;
  float v3a2 = (qa.y * ba.z - qa.z * ba.y) * INV_SQRT2;
  float v3b0 = (qb.z * bb.w - qb.w * bb.z) * INV_SQRT2;
  float v3b1 = (qb.w * bb.y - qb.y * bb.w) * INV_SQRT2;
  float v3b2 = (qb.y * bb.z - qb.z * bb.y) * INV_SQRT2;

  // norm sums within 8-lane group
  float p1 = s1a * s1a + s1b * s1b;
  float p2 = s2a * s2a + s2b * s2b;
  float p3 = v1a0 * v1a0 + v1a1 * v1a1 + v1a2 * v1a2 + v1b0 * v1b0 + v1b1 * v1b1 + v1b2 * v1b2;
  float p4 = v2a0 * v2a0 + v2a1 * v2a1 + v2a2 * v2a2 + v2b0 * v2b0 + v2b1 * v2b1 + v2b2 * v2b2;
  float p5 = v3a0 * v3a0 + v3a1 * v3a1 + v3a2 * v3a2 + v3b0 * v3b0 + v3b1 * v3b1 + v3b2 * v3b2;
#pragma unroll
  for (int msk = 1; msk <= 4; msk <<= 1) {
    p1 += __shfl_xor(p1, msk);
    p2 += __shfl_xor(p2, msk);
    p3 += __shfl_xor(p3, msk);
    p4 += __shfl_xor(p4, msk);
    p5 += __shfl_xor(p5, msk);
  }
  float r1 = rsqrtf(p1 * (1.f / 16) + EPSN);
  float r2 = rsqrtf(p2 * (1.f / 16) + EPSN);
  float rv1 = rsqrtf(p3 * (1.f / 48) + EPSN);
  float rv2 = rsqrtf(p4 * (1.f / 48) + EPSN);
  float rv3 = rsqrtf(p5 * (1.f / 48) + EPSN);

  // sci (interleaved s1,s2) -> LDS; v1|v2|v3 -> LDS (bank-staggered base)
  {
    float* sp = SCI + g * 36 + 4 * r;
    sp[0] = s1a * r1; sp[1] = s2a * r2; sp[2] = s1b * r1; sp[3] = s2b * r2;
    float* vb = UN + g * 260;  // g*256 + 4g: groups 4 banks apart
    vb[6 * r + 0] = v1a0 * rv1; vb[6 * r + 1] = v1a1 * rv1; vb[6 * r + 2] = v1a2 * rv1;
    vb[6 * r + 3] = v1b0 * rv1; vb[6 * r + 4] = v1b1 * rv1; vb[6 * r + 5] = v1b2 * rv1;
    float* v2p = vb + 48;
    v2p[6 * r + 0] = v2a0 * rv2; v2p[6 * r + 1] = v2a1 * rv2; v2p[6 * r + 2] = v2a2 * rv2;
    v2p[6 * r + 3] = v2b0 * rv2; v2p[6 * r + 4] = v2b1 * rv2; v2p[6 * r + 5] = v2b2 * rv2;
    float* v3p = vb + 96;
    v3p[6 * r + 0] = v3a0 * rv3; v3p[6 * r + 1] = v3a1 * rv3; v3p[6 * r + 2] = v3a2 * rv3;
    v3p[6 * r + 3] = v3b0 * rv3; v3p[6 * r + 4] = v3b1 * rv3; v3p[6 * r + 5] = v3b2 * rv3;
  }

  // ---- eq_s + eq_v outputs (cols r and r+8 of each) ----
  {
    float es0 = 0.f, es1 = 0.f;
#pragma unroll
    for (int i = 0; i < 16; i++) {
      float s1i = SCI[g * 36 + 2 * i], s2i = SCI[g * 36 + 2 * i + 1];
      es0 += s1i * weqs[i * 16 + r] + s2i * weqs[(16 + i) * 16 + r];
      es1 += s1i * weqs[i * 16 + r + 8] + s2i * weqs[(16 + i) * 16 + r + 8];
    }
    float ev0[3] = {0.f, 0.f, 0.f}, ev1[3] = {0.f, 0.f, 0.f};
    const float* vb = UN + g * 260;
#pragma unroll
    for (int i = 0; i < 16; i++) {
      float w1a = weqv[i * 16 + r], w1b = weqv[i * 16 + r + 8];
      float w2a = weqv[(16 + i) * 16 + r], w2b = weqv[(16 + i) * 16 + r + 8];
      float w3a = weqv[(32 + i) * 16 + r], w3b = weqv[(32 + i) * 16 + r + 8];
#pragma unroll
      for (int d = 0; d < 3; d++) {
        float x1 = vb[3 * i + d], x2 = vb[48 + 3 * i + d], x3 = vb[96 + 3 * i + d];
        ev0[d] += x1 * w1a + x2 * w2a + x3 * w3a;
        ev1[d] += x1 * w1b + x2 * w2b + x3 * w3b;
      }
    }
    ((float4*)oute)[(size_t)e * 16 + r] = make_float4(es0, ev0[0], ev0[1], ev0[2]);
    ((float4*)oute)[(size_t)e * 16 + r + 8] = make_float4(es1, ev1[0], ev1[1], ev1[2]);
  }

  // ---- sc MLP: layer1 (32 -> 128), lane owns cols 2l,2l+1 ----
  float aa[8][2];
  {
    float2 bb1v = ((const float2*)scb1)[lane];
#pragma unroll
    for (int j = 0; j < 8; j++) { aa[j][0] = bb1v.x; aa[j][1] = bb1v.y; }
    for (int i = 0; i < 32; i += 2) {
      float2 wv0 = ((const float2*)scw1)[(size_t)i * 64 + lane];
      float2 wv1 = ((const float2*)scw1)[(size_t)(i + 1) * 64 + lane];
#pragma unroll
      for (int j = 0; j < 8; j++) {
        float2 xv = *(const float2*)(SCI + j * 36 + i);
        aa[j][0] += xv.x * wv0.x + xv.y * wv1.x;
        aa[j][1] += xv.x * wv0.y + xv.y * wv1.y;
      }
    }
#pragma unroll
    for (int j = 0; j < 8; j++)
      ((float2*)(UN + j * 256))[lane] = make_float2(silu(aa[j][0]), silu(aa[j][1]));
  }
  // ---- layer2 (128 -> 128), h1 -> h2 ----
  {
    float2 bb2v = ((const float2*)scb2)[lane];
#pragma unroll
    for (int j = 0; j < 8; j++) { aa[j][0] = bb2v.x; aa[j][1] = bb2v.y; }
    for (int i = 0; i < 128; i += 2) {
      float2 wv0 = ((const float2*)scw2)[(size_t)i * 64 + lane];
      float2 wv1 = ((const float2*)scw2)[(size_t)(i + 1) * 64 + lane];
#pragma unroll
      for (int j = 0; j < 8; j++) {
        float2 xv = *(const float2*)(UN + j * 256 + i);
        aa[j][0] += xv.x * wv0.x + xv.y * wv1.x;
        aa[j][1] += xv.x * wv0.y + xv.y * wv1.y;
      }
    }
#pragma unroll
    for (int j = 0; j < 8; j++)
      ((float2*)(UN + j * 256 + 128))[lane] = make_float2(silu(aa[j][0]), silu(aa[j][1]));
  }
  // ---- layer3 (128 -> 128), no activation ----
  {
    float2 bb3v = ((const float2*)scb3)[lane];
#pragma unroll
    for (int j = 0; j < 8; j++) { aa[j][0] = bb3v.x; aa[j][1] = bb3v.y; }
    for (int i = 0; i < 128; i += 2) {
      float2 wv0 = ((const float2*)scw3)[(size_t)i * 64 + lane];
      float2 wv1 = ((const float2*)scw3)[(size_t)(i + 1) * 64 + lane];
#pragma unroll
      for (int j = 0; j < 8; j++) {
        float2 xv = *(const float2*)(UN + j * 256 + 128 + i);
        aa[j][0] += xv.x * wv0.x + xv.y * wv1.x;
        aa[j][1] += xv.x * wv0.y + xv.y * wv1.y;
      }
    }
  }
  // ---- LayerNorm + residual write ----
  {
    float2 lg2 = ((const float2*)lng)[lane], lb2 = ((const float2*)lnb)[lane];
    float ucv = ucoef[0];
    float co = rsqrtf(ucv * ucv + 1.f), cn = ucv * co;
#pragma unroll
    for (int j = 0; j < 8; j++) {
      float o0 = aa[j][0], o1 = aa[j][1];
      float sm = wsum64(o0 + o1);
      float sq = wsum64(o0 * o0 + o1 * o1);
      float mu = sm * (1.f / 128);
      float var = sq * (1.f / 128) - mu * mu;
      float rsn = rsqrtf(var + EPSN);
      float n0 = (o0 - mu) * rsn * lg2.x + lb2.x;
      float n1 = (o1 - mu) * rsn * lg2.y + lb2.y;
      int ae = act[e0 + j];
      float2 xv = ((const float2*)scal)[(size_t)ae * 64 + lane];
      ((float2*)outs)[(size_t)ae * 64 + lane] =
          make_float2(co * xv.x + cn * n0, co * xv.y + cn * n1);
    }
  }
}

extern "C" void kernel_launch(void* const* d_in, const int* in_sizes, int n_in,
                              void* d_out, int out_size, void* d_ws,
                              size_t ws_size, hipStream_t stream) {
  const float* ninv = (const float*)d_in[0];
  const float* scal = (const float*)d_in[1];
  const float* equiv = (const float*)d_in[2];
  const int* eidx = (const int*)d_in[3];
  const int* act = (const int*)d_in[4];
  const float* uc = (const float*)d_in[5];
  const float* ew1 = (const float*)d_in[6];
  const float* eb1 = (const float*)d_in[7];
  const float* ew2 = (const float*)d_in[8];
  const float* eb2 = (const float*)d_in[9];
  const float* ew3 = (const float*)d_in[10];
  const float* eb3 = (const float*)d_in[11];
  const float* wq = (const float*)d_in[12];
  const float* wk = (const float*)d_in[13];
  const float* sw1 = (const float*)d_in[14];
  const float* sb1 = (const float*)d_in[15];
  const float* sw2 = (const float*)d_in[16];
  const float* sb2 = (const float*)d_in[17];
  const float* sw3 = (const float*)d_in[18];
  const float* sb3 = (const float*)d_in[19];
  const float* lng = (const float*)d_in[20];
  const float* lnb = (const float*)d_in[21];
  const float* weqs = (const float*)d_in[22];
  const float* weqv = (const float*)d_in[23];

  float* outs = (float*)d_out;
  float* oute = outs + (size_t)EE * 128;

  float* ws = (float*)d_ws;
  float* gates = ws;                                       // E*32
  float* logits = ws + (size_t)EE * 32;                    // E*16
  unsigned* nmax = (unsigned*)(ws + (size_t)EE * 48);      // N*16
  float* nsum = ws + (size_t)EE * 48 + (size_t)NN * 16;    // N*16
  float* nds = ws + (size_t)EE * 48 + (size_t)NN * 32;     // N*16
  float* ndv = ws + (size_t)EE * 48 + (size_t)NN * 48;     // N*48
  float* ndb = ws + (size_t)EE * 48 + (size_t)NN * 96;     // N*64 packed

  const int* ecent = eidx;

  hipLaunchKernelGGL(k_init, dim3((NN * 48 + 255) / 256), dim3(256), 0, stream,
                     nmax, nsum, nds, ndv);
  hipLaunchKernelGGL(k_edge_front, dim3(EE / 32), dim3(256), 0, stream, scal,
                     ninv, ecent, ew1, eb1, ew2, eb2, ew3, eb3, wq, wk, gates,
                     logits, nmax);
  hipLaunchKernelGGL(k_scatter, dim3(EE * 16 / 256), dim3(256), 0, stream,
                     ecent, logits, nmax, gates, equiv, nsum, nds, ndv);
  hipLaunchKernelGGL(k_nodenorm, dim3(NN / 4), dim3(256), 0, stream, nds, ndv,
                     nsum, ndb);
  hipLaunchKernelGGL(k_edge_back, dim3(EE / 32), dim3(256), 0, stream, scal,
                     equiv, ecent, act, uc, ndb, sw1, sb1, sw2, sb2, sw3, sb3,
                     lng, lnb, weqs, weqv, outs, oute);
}